// Round 5
// baseline (172.268 us; speedup 1.0000x reference)
//
#include <hip/hip_runtime.h>
#include <hip/hip_bf16.h>

// out[b,d,r] = sum_c p[b,c] * softmax_d( x[b,:] @ W[:, c*8+d, r] + bias[c,d,r] )
// B=16384, F=128, C=8, R=64.  bf16 MFMA 16x16x32, fully fused.
//
// R3->R4: true per-wave regs were ~arch(88)+acc(64) => only 8 waves/CU
// resident.  Re-map N-axis so the 8 d-values sit INSIDE one 16-col MFMA
// tile (col bits: d={b0,b1,b3}, r-parity=b2).  Softmax-over-d = 3 DPP adds
// (quad_perm xor1/xor2 + row_ror:8).  acc: 32->4 regs, O: 32->4 regs.
// 256-thr blocks, grid 1024, launch_bounds(256,4) => 128-reg budget.
// R4->R5: update_dpp ctrl must be an ICE -> template parameter.

#define B_ROWS   16384
#define F_DIM    128
#define NCOL     4096      // C*C*R
#define OUT_STRIDE 512     // C*R
#define LOG2E    1.44269504088896340736f

typedef __bf16 bf16x8 __attribute__((ext_vector_type(8)));
typedef float  f32x4  __attribute__((ext_vector_type(4)));

// DPP-assisted partial-group add: s + permute(s).  CTRL: 0xB1 = quad_perm
// [1,0,3,2] (xor1), 0x4E = quad_perm [2,3,0,1] (xor2), 0x128 = row_ror:8
// (== xor8 within a 16-lane row).
template <int CTRL>
__device__ __forceinline__ float dpp_add(float s) {
    int si = __builtin_bit_cast(int, s);
    int pi = __builtin_amdgcn_update_dpp(0, si, CTRL, 0xf, 0xf, true);
    return s + __builtin_bit_cast(float, pi);
}

// Kernel-column mapping: tile T in [0,256) = c*32 + w*8 + i; col4 in [0,16):
//   d = (col4&3) | ((col4>>1)&4)     (bits 0,1,3 of col4)
//   r = w*16 + i*2 + ((col4>>2)&1)   (bit 2 of col4 = r parity)
// Original W column n_orig = (c*8+d)*64 + r.

// ---------------------------------------------------------------------------
// Prepass: W fp32 (128 x 4096) -> bf16 MFMA B-fragments (permuted cols).
// One thread per (T,kk,lane): 8 reads, one 16B coalesced store.
// ---------------------------------------------------------------------------
__global__ void wconv_kernel(const float* __restrict__ W, __bf16* __restrict__ wf) {
    int f    = blockIdx.x * 256 + threadIdx.x;  // 0..65535
    int lane = f & 63;
    int tkk  = f >> 6;
    int T    = tkk >> 2;
    int kk   = tkk & 3;
    int c    = T >> 5;
    int w    = (T >> 3) & 3;
    int i    = T & 7;
    int col4 = lane & 15;
    int d    = (col4 & 3) | ((col4 >> 1) & 4);
    int r    = w * 16 + i * 2 + ((col4 >> 2) & 1);
    int n    = (c * 8 + d) * 64 + r;
    int kbase = kk * 32 + (lane >> 4) * 8;
    bf16x8 frag;
    for (int j = 0; j < 8; ++j)
        frag[j] = (__bf16)W[(kbase + j) * NCOL + n];
    *(bf16x8*)(wf + f * 8) = frag;
}

// ---------------------------------------------------------------------------
// Fused GEMM + bias + softmax(d) + p-contraction.
// Block: 256 thr (4 waves), 16 batch rows; wave w owns r in [16w,16w+16).
// Per (i,c) tile: 4-MFMA chain -> per-jj: exp2, 8-lane DPP sum, p/s scale.
// ---------------------------------------------------------------------------
__global__ __launch_bounds__(256, 4)
void fused_kernel(const float* __restrict__ x, const float* __restrict__ p,
                  const float* __restrict__ bias, const __bf16* __restrict__ wf,
                  float* __restrict__ out) {
    const int lane = threadIdx.x & 63;
    const int w    = threadIdx.x >> 6;   // r-chunk 0..3
    const int quad = lane >> 4;
    const int l15  = lane & 15;
    const int b0   = blockIdx.x * 16;
    const int d    = (l15 & 3) | ((l15 >> 1) & 4);
    const int rb   = (l15 >> 2) & 1;

    // A fragments: afr[kk][j] = x_bf16[b0+l15][kk*32 + quad*8 + j]
    bf16x8 afr[4];
    {
        const float* xr = x + (b0 + l15) * F_DIM + quad * 8;
#pragma unroll
        for (int kk = 0; kk < 4; ++kk) {
            float4 lo = *(const float4*)(xr + kk * 32);
            float4 hi = *(const float4*)(xr + kk * 32 + 4);
            bf16x8 f;
            f[0] = (__bf16)lo.x; f[1] = (__bf16)lo.y;
            f[2] = (__bf16)lo.z; f[3] = (__bf16)lo.w;
            f[4] = (__bf16)hi.x; f[5] = (__bf16)hi.y;
            f[6] = (__bf16)hi.z; f[7] = (__bf16)hi.w;
            afr[kk] = f;
        }
    }

    // p for this lane's 4 rows x 8 classes (compile-time indexed only)
    float pv[8][4];
#pragma unroll
    for (int c = 0; c < 8; ++c)
#pragma unroll
        for (int jj = 0; jj < 4; ++jj)
            pv[c][jj] = p[(b0 + quad * 4 + jj) * 8 + c];

#pragma unroll 1
    for (int i = 0; i < 8; ++i) {
        const int r = w * 16 + i * 2 + rb;

        float bvl[8];
#pragma unroll
        for (int c = 0; c < 8; ++c)
            bvl[c] = bias[(c * 8 + d) * 64 + r] * LOG2E;

        float O[4] = {0.f, 0.f, 0.f, 0.f};

#pragma unroll
        for (int c = 0; c < 8; ++c) {
            const int T = c * 32 + w * 8 + i;
            f32x4 acc = {0.f, 0.f, 0.f, 0.f};
#pragma unroll
            for (int kk = 0; kk < 4; ++kk) {
                bf16x8 bfr = *(const bf16x8*)(wf + (((T << 2) + kk) * 64 + lane) * 8);
                acc = __builtin_amdgcn_mfma_f32_16x16x32_bf16(afr[kk], bfr, acc, 0, 0, 0);
            }
#pragma unroll
            for (int jj = 0; jj < 4; ++jj) {
                float e = __builtin_amdgcn_exp2f(
                              __builtin_fmaf(acc[jj], LOG2E, bvl[c]));
                float s = dpp_add<0xB1>(e);    // + xor1 (d bit 0)
                s = dpp_add<0x4E>(s);          // + xor2 (d bit 1)
                s = dpp_add<0x128>(s);         // + xor8 (d bit 2)
                O[jj] = __builtin_fmaf(e, pv[c][jj] * __builtin_amdgcn_rcpf(s), O[jj]);
            }
        }

#pragma unroll
        for (int jj = 0; jj < 4; ++jj)
            out[(b0 + quad * 4 + jj) * OUT_STRIDE + d * 64 + r] = O[jj];
    }
}

extern "C" void kernel_launch(void* const* d_in, const int* in_sizes, int n_in,
                              void* d_out, int out_size, void* d_ws, size_t ws_size,
                              hipStream_t stream) {
    const float* x    = (const float*)d_in[0];   // (16384, 128)
    const float* p    = (const float*)d_in[1];   // (16384, 8)
    const float* W    = (const float*)d_in[2];   // (128, 64, 64)
    const float* bias = (const float*)d_in[3];   // (8, 8, 64)
    float* out = (float*)d_out;                  // (16384, 8, 64)
    __bf16* wf = (__bf16*)d_ws;                  // 1 MB bf16 fragments

    wconv_kernel<<<dim3(256), dim3(256), 0, stream>>>(W, wf);
    fused_kernel<<<dim3(B_ROWS / 16), dim3(256), 0, stream>>>(x, p, bias, wf, out);
}

// Round 6
// 144.141 us; speedup vs baseline: 1.1951x; 1.1951x over previous
//
#include <hip/hip_runtime.h>
#include <hip/hip_bf16.h>

// out[b,d,r] = sum_c p[b,c] * softmax_d( x[b,:] @ W[:, c*8+d, r] + bias[c,d,r] )
// B=16384, F=128, C=8, R=64.  bf16 MFMA 16x16x32, fully fused.
//
// R5->R6: R5 was write-amplification-bound (WRITE_SIZE 160 MB = 4.8x ideal,
// 4B stores scattered at 256B stride -> partial-sector HBM writes).  Now O
// is buffered across all 8 i-iters (O_all[8][4]) and transposed in-register
// at the end (ds_swizzle xor-4 exchanges the rb lane pair, cndmask repack)
// so each lane stores 8 consecutive floats -> 2x global_store_dwordx4/row.
// Loops: c outer (unroll 1, pv scalar per c), i inner (full unroll, static
// O_all indices).  Live regs ~95 < 128 (launch_bounds(256,4) budget).

#define B_ROWS   16384
#define F_DIM    128
#define NCOL     4096      // C*C*R
#define OUT_STRIDE 512     // C*R
#define LOG2E    1.44269504088896340736f

typedef __bf16 bf16x8 __attribute__((ext_vector_type(8)));
typedef float  f32x4  __attribute__((ext_vector_type(4)));

// DPP-assisted partial-group add: s + permute(s).  CTRL: 0xB1 = quad_perm
// [1,0,3,2] (xor1), 0x4E = quad_perm [2,3,0,1] (xor2), 0x128 = row_ror:8
// (== xor8 within a 16-lane row).
template <int CTRL>
__device__ __forceinline__ float dpp_add(float s) {
    int si = __builtin_bit_cast(int, s);
    int pi = __builtin_amdgcn_update_dpp(0, si, CTRL, 0xf, 0xf, true);
    return s + __builtin_bit_cast(float, pi);
}

// xor-4 lane swizzle (exchanges the rb pair; keeps quad and d bits 0,1,3).
// BitMode offset = (xor_mask<<10) | 0x1F = 0x101F.
__device__ __forceinline__ float swz4(float v) {
    return __builtin_bit_cast(float,
        __builtin_amdgcn_ds_swizzle(__builtin_bit_cast(int, v), 0x101F));
}

// Kernel-column mapping: tile T in [0,256) = c*32 + w*8 + i; col4 in [0,16):
//   d = (col4&3) | ((col4>>1)&4)     (bits 0,1,3 of col4)
//   r = w*16 + i*2 + ((col4>>2)&1)   (bit 2 of col4 = r parity)
// Original W column n_orig = (c*8+d)*64 + r.

// ---------------------------------------------------------------------------
// Prepass: W fp32 (128 x 4096) -> bf16 MFMA B-fragments (permuted cols).
// ---------------------------------------------------------------------------
__global__ void wconv_kernel(const float* __restrict__ W, __bf16* __restrict__ wf) {
    int f    = blockIdx.x * 256 + threadIdx.x;  // 0..65535
    int lane = f & 63;
    int tkk  = f >> 6;
    int T    = tkk >> 2;
    int kk   = tkk & 3;
    int c    = T >> 5;
    int w    = (T >> 3) & 3;
    int i    = T & 7;
    int col4 = lane & 15;
    int d    = (col4 & 3) | ((col4 >> 1) & 4);
    int r    = w * 16 + i * 2 + ((col4 >> 2) & 1);
    int n    = (c * 8 + d) * 64 + r;
    int kbase = kk * 32 + (lane >> 4) * 8;
    bf16x8 frag;
    for (int j = 0; j < 8; ++j)
        frag[j] = (__bf16)W[(kbase + j) * NCOL + n];
    *(bf16x8*)(wf + f * 8) = frag;
}

// ---------------------------------------------------------------------------
// Fused GEMM + bias + softmax(d) + p-contraction + in-register transpose.
// Block: 256 thr (4 waves), 16 batch rows; wave w owns r in [16w,16w+16).
// ---------------------------------------------------------------------------
__global__ __launch_bounds__(256, 4)
void fused_kernel(const float* __restrict__ x, const float* __restrict__ p,
                  const float* __restrict__ bias, const __bf16* __restrict__ wf,
                  float* __restrict__ out) {
    const int lane = threadIdx.x & 63;
    const int w    = threadIdx.x >> 6;   // r-chunk 0..3
    const int quad = lane >> 4;
    const int l15  = lane & 15;
    const int b0   = blockIdx.x * 16;
    const int d    = (l15 & 3) | ((l15 >> 1) & 4);
    const int rb   = (l15 >> 2) & 1;     // source: r parity; target: 8-col half

    // A fragments: afr[kk][j] = x_bf16[b0+l15][kk*32 + quad*8 + j]
    bf16x8 afr[4];
    {
        const float* xr = x + (b0 + l15) * F_DIM + quad * 8;
#pragma unroll
        for (int kk = 0; kk < 4; ++kk) {
            float4 lo = *(const float4*)(xr + kk * 32);
            float4 hi = *(const float4*)(xr + kk * 32 + 4);
            bf16x8 f;
            f[0] = (__bf16)lo.x; f[1] = (__bf16)lo.y;
            f[2] = (__bf16)lo.z; f[3] = (__bf16)lo.w;
            f[4] = (__bf16)hi.x; f[5] = (__bf16)hi.y;
            f[6] = (__bf16)hi.z; f[7] = (__bf16)hi.w;
            afr[kk] = f;
        }
    }

    float O_all[8][4] = {};   // [i][jj], static-indexed (i fully unrolled)

#pragma unroll 1
    for (int c = 0; c < 8; ++c) {
        float pv[4];
#pragma unroll
        for (int jj = 0; jj < 4; ++jj)
            pv[jj] = p[(b0 + quad * 4 + jj) * 8 + c];

#pragma unroll
        for (int i = 0; i < 8; ++i) {
            const int r = w * 16 + i * 2 + rb;
            float bvl = bias[(c * 8 + d) * 64 + r] * LOG2E;

            const int T = c * 32 + w * 8 + i;
            f32x4 acc = {0.f, 0.f, 0.f, 0.f};
#pragma unroll
            for (int kk = 0; kk < 4; ++kk) {
                bf16x8 bfr = *(const bf16x8*)(wf + (((T << 2) + kk) * 64 + lane) * 8);
                acc = __builtin_amdgcn_mfma_f32_16x16x32_bf16(afr[kk], bfr, acc, 0, 0, 0);
            }
#pragma unroll
            for (int jj = 0; jj < 4; ++jj) {
                float e = __builtin_amdgcn_exp2f(
                              __builtin_fmaf(acc[jj], LOG2E, bvl));
                float s = dpp_add<0xB1>(e);    // + xor1 (d bit 0)
                s = dpp_add<0x4E>(s);          // + xor2 (d bit 1)
                s = dpp_add<0x128>(s);         // + xor8 (d bit 2)
                O_all[i][jj] = __builtin_fmaf(
                    e, pv[jj] * __builtin_amdgcn_rcpf(s), O_all[i][jj]);
            }
        }
    }

    // ---- transpose (rb pair exchange) + coalesced stores -------------------
    // Source: lane(rb) reg i holds sub-offset 2i+rb (within this d's 16-col
    // span at w*16).  Target: lane(h=rb-bit) reg m holds sub-offset 8h+m.
    const bool bhi = (rb != 0);
#pragma unroll
    for (int jj = 0; jj < 4; ++jj) {
        float S[8];
#pragma unroll
        for (int i = 0; i < 8; ++i)
            S[i] = swz4(O_all[i][jj]);
        float T[8];
#pragma unroll
        for (int m = 0; m < 8; ++m) {
            int ilo = m >> 1, ihi = 4 + (m >> 1);
            float tlo = (m & 1) ? S[ilo]        : O_all[ilo][jj];
            float thi = (m & 1) ? O_all[ihi][jj] : S[ihi];
            T[m] = bhi ? thi : tlo;
        }
        float* orow = out + (b0 + quad * 4 + jj) * OUT_STRIDE
                          + d * 64 + w * 16 + rb * 8;
        f32x4 v0 = {T[0], T[1], T[2], T[3]};
        f32x4 v1 = {T[4], T[5], T[6], T[7]};
        *(f32x4*)(orow)     = v0;
        *(f32x4*)(orow + 4) = v1;
    }
}

extern "C" void kernel_launch(void* const* d_in, const int* in_sizes, int n_in,
                              void* d_out, int out_size, void* d_ws, size_t ws_size,
                              hipStream_t stream) {
    const float* x    = (const float*)d_in[0];   // (16384, 128)
    const float* p    = (const float*)d_in[1];   // (16384, 8)
    const float* W    = (const float*)d_in[2];   // (128, 64, 64)
    const float* bias = (const float*)d_in[3];   // (8, 8, 64)
    float* out = (float*)d_out;                  // (16384, 8, 64)
    __bf16* wf = (__bf16*)d_ws;                  // 1 MB bf16 fragments

    wconv_kernel<<<dim3(256), dim3(256), 0, stream>>>(W, wf);
    fused_kernel<<<dim3(B_ROWS / 16), dim3(256), 0, stream>>>(x, p, bias, wf, out);
}

// Round 7
// 111.403 us; speedup vs baseline: 1.5464x; 1.2939x over previous
//
#include <hip/hip_runtime.h>
#include <hip/hip_bf16.h>

// out[b,d,r] = sum_c p[b,c] * softmax_d( x[b,:] @ W[:, c*8+d, r] + bias[c,d,r] )
// B=16384, F=128, C=8, R=64.  bf16 MFMA 16x16x32, fully fused.
//
// R6->R7: R6 was latency-bound (VALUBusy 19%): each block re-read the whole
// 1 MB wf (1 GB L1/L2 traffic total) through a tiny VGPR in-flight window.
// Now block = 64 rows x ONE r-chunk w; all 4 waves share w's fragments,
// staged per-c into LDS with async global_load_lds width=16 (32 KB wf +
// 2 KB pre-swizzled bias, single buffer, 2 barriers/c).  wf traffic 4x down
// (256 MB), load latency decoupled from VGPRs.  Stores = R6's verified
// in-register transpose.  LDS 34 KB -> 4 blocks/CU (16 waves/CU).

#define B_ROWS   16384
#define F_DIM    128
#define NCOL     4096      // C*C*R
#define OUT_STRIDE 512     // C*R
#define LOG2E    1.44269504088896340736f

typedef __bf16 bf16x8 __attribute__((ext_vector_type(8)));
typedef float  f32x4  __attribute__((ext_vector_type(4)));

#define AS1(p) ((const __attribute__((address_space(1))) unsigned int*)(p))
#define AS3(p) ((__attribute__((address_space(3))) unsigned int*)(p))

// DPP-assisted partial-group add: s + permute(s).  CTRL: 0xB1 = quad_perm
// [1,0,3,2] (xor1), 0x4E = quad_perm [2,3,0,1] (xor2), 0x128 = row_ror:8.
template <int CTRL>
__device__ __forceinline__ float dpp_add(float s) {
    int si = __builtin_bit_cast(int, s);
    int pi = __builtin_amdgcn_update_dpp(0, si, CTRL, 0xf, 0xf, true);
    return s + __builtin_bit_cast(float, pi);
}

// xor-4 lane swizzle (exchanges the rb pair).  BitMode offset 0x101F.
__device__ __forceinline__ float swz4(float v) {
    return __builtin_bit_cast(float,
        __builtin_amdgcn_ds_swizzle(__builtin_bit_cast(int, v), 0x101F));
}

// Column mapping: tile T in [0,256) = c*32 + w*8 + i; col4 in [0,16):
//   d = (col4&3) | ((col4>>1)&4) ; r = w*16 + i*2 + ((col4>>2)&1)
// Original W column n_orig = (c*8+d)*64 + r.

// ---------------------------------------------------------------------------
// Prepass 1: W fp32 (128 x 4096) -> bf16 MFMA B-fragments (permuted cols).
// Fragment index g = c*128 + w*32 + i*4 + kk; element (g, lane, j).
// ---------------------------------------------------------------------------
__global__ void wconv_kernel(const float* __restrict__ W, __bf16* __restrict__ wf) {
    int f    = blockIdx.x * 256 + threadIdx.x;  // 0..65535
    int lane = f & 63;
    int tkk  = f >> 6;
    int T    = tkk >> 2;
    int kk   = tkk & 3;
    int c    = T >> 5;
    int w    = (T >> 3) & 3;
    int i    = T & 7;
    int col4 = lane & 15;
    int d    = (col4 & 3) | ((col4 >> 1) & 4);
    int r    = w * 16 + i * 2 + ((col4 >> 2) & 1);
    int n    = (c * 8 + d) * 64 + r;
    int kbase = kk * 32 + (lane >> 4) * 8;
    bf16x8 frag;
    for (int j = 0; j < 8; ++j)
        frag[j] = (__bf16)W[(kbase + j) * NCOL + n];
    *(bf16x8*)(wf + f * 8) = frag;
}

// ---------------------------------------------------------------------------
// Prepass 2: bias -> fragment-lane order, pre-scaled by log2(e).
// bs[T*64 + lane] = bias[(c*8+d)*64 + r] * LOG2E
// ---------------------------------------------------------------------------
__global__ void bconv_kernel(const float* __restrict__ bias, float* __restrict__ bs) {
    int t    = blockIdx.x * 256 + threadIdx.x;  // 0..16383
    int lane = t & 63;
    int T    = t >> 6;
    int c    = T >> 5;
    int w    = (T >> 3) & 3;
    int i    = T & 7;
    int col4 = lane & 15;
    int d    = (col4 & 3) | ((col4 >> 1) & 4);
    int r    = w * 16 + i * 2 + ((col4 >> 2) & 1);
    bs[t] = bias[(c * 8 + d) * 64 + r] * LOG2E;
}

// ---------------------------------------------------------------------------
// Fused GEMM + bias + softmax(d) + p-contraction + in-register transpose.
// Block: 256 thr (4 waves), 64 batch rows, one r-chunk w = blockIdx&3.
// Wave ww owns rows b0+ww*16..+16; all waves share the per-c LDS fragments.
// ---------------------------------------------------------------------------
__global__ __launch_bounds__(256, 4)
void fused_kernel(const float* __restrict__ x, const float* __restrict__ p,
                  const float* __restrict__ bs, const __bf16* __restrict__ wf,
                  float* __restrict__ out) {
    __shared__ __align__(16) char lds[32768 + 2048];   // 32 frags + bias slab

    const int lane = threadIdx.x & 63;
    const int ww   = threadIdx.x >> 6;   // wave 0..3 = m-tile
    const int quad = lane >> 4;
    const int l15  = lane & 15;
    const int w    = blockIdx.x & 3;     // r-chunk
    const int b0   = (blockIdx.x >> 2) * 64 + ww * 16;
    const int d    = (l15 & 3) | ((l15 >> 1) & 4);
    const int rb   = (l15 >> 2) & 1;

    // A fragments: afr[kk][j] = x_bf16[b0+l15][kk*32 + quad*8 + j]
    bf16x8 afr[4];
    {
        const float* xr = x + (b0 + l15) * F_DIM + quad * 8;
#pragma unroll
        for (int kk = 0; kk < 4; ++kk) {
            float4 lo = *(const float4*)(xr + kk * 32);
            float4 hi = *(const float4*)(xr + kk * 32 + 4);
            bf16x8 f;
            f[0] = (__bf16)lo.x; f[1] = (__bf16)lo.y;
            f[2] = (__bf16)lo.z; f[3] = (__bf16)lo.w;
            f[4] = (__bf16)hi.x; f[5] = (__bf16)hi.y;
            f[6] = (__bf16)hi.z; f[7] = (__bf16)hi.w;
            afr[kk] = f;
        }
    }

    float O_all[8][4] = {};   // [i][jj], static-indexed (i fully unrolled)

#pragma unroll 1
    for (int c = 0; c < 8; ++c) {
        // ---- async stage: wave ww stages fragments f = ww*8..ww*8+7 -------
        // global frag g = c*128 + w*32 + f ; 512 bf16 each; lane takes 16 B.
        {
            const __bf16* gbase = wf + (size_t)(c * 128 + w * 32) * 512 + lane * 8;
#pragma unroll
            for (int j = 0; j < 8; ++j) {
                int f = ww * 8 + j;
                __builtin_amdgcn_global_load_lds(AS1(gbase + f * 512),
                                                 AS3(lds + f * 1024), 16, 0, 0);
            }
            if (ww == 0) {   // bias slab: 512 floats = 2 width-16 issues
                const float* gb = bs + (c * 32 + w * 8) * 64 + lane * 4;
#pragma unroll
                for (int h = 0; h < 2; ++h)
                    __builtin_amdgcn_global_load_lds(AS1(gb + h * 256),
                                                     AS3(lds + 32768 + h * 1024), 16, 0, 0);
            }
        }
        __syncthreads();

        float pvv[4];
#pragma unroll
        for (int jj = 0; jj < 4; ++jj)
            pvv[jj] = p[(b0 + quad * 4 + jj) * 8 + c];

#pragma unroll
        for (int i = 0; i < 8; ++i) {
            f32x4 acc = {0.f, 0.f, 0.f, 0.f};
#pragma unroll
            for (int kk = 0; kk < 4; ++kk) {
                bf16x8 bfr = *(const bf16x8*)(lds + (i * 4 + kk) * 1024 + lane * 16);
                acc = __builtin_amdgcn_mfma_f32_16x16x32_bf16(afr[kk], bfr, acc, 0, 0, 0);
            }
            float bvl = *(const float*)(lds + 32768 + (i * 64 + lane) * 4);
#pragma unroll
            for (int jj = 0; jj < 4; ++jj) {
                float e = __builtin_amdgcn_exp2f(
                              __builtin_fmaf(acc[jj], LOG2E, bvl));
                float s = dpp_add<0xB1>(e);    // + xor1 (d bit 0)
                s = dpp_add<0x4E>(s);          // + xor2 (d bit 1)
                s = dpp_add<0x128>(s);         // + xor8 (d bit 2)
                O_all[i][jj] = __builtin_fmaf(
                    e, pvv[jj] * __builtin_amdgcn_rcpf(s), O_all[i][jj]);
            }
        }
        __syncthreads();   // protect LDS before next c's staging
    }

    // ---- transpose (rb pair exchange) + coalesced stores -------------------
    const bool bhi = (rb != 0);
#pragma unroll
    for (int jj = 0; jj < 4; ++jj) {
        float S[8];
#pragma unroll
        for (int i = 0; i < 8; ++i)
            S[i] = swz4(O_all[i][jj]);
        float T[8];
#pragma unroll
        for (int m = 0; m < 8; ++m) {
            int ilo = m >> 1, ihi = 4 + (m >> 1);
            float tlo = (m & 1) ? S[ilo]         : O_all[ilo][jj];
            float thi = (m & 1) ? O_all[ihi][jj] : S[ihi];
            T[m] = bhi ? thi : tlo;
        }
        float* orow = out + (b0 + quad * 4 + jj) * OUT_STRIDE
                          + d * 64 + w * 16 + rb * 8;
        f32x4 v0 = {T[0], T[1], T[2], T[3]};
        f32x4 v1 = {T[4], T[5], T[6], T[7]};
        *(f32x4*)(orow)     = v0;
        *(f32x4*)(orow + 4) = v1;
    }
}

extern "C" void kernel_launch(void* const* d_in, const int* in_sizes, int n_in,
                              void* d_out, int out_size, void* d_ws, size_t ws_size,
                              hipStream_t stream) {
    const float* x    = (const float*)d_in[0];   // (16384, 128)
    const float* p    = (const float*)d_in[1];   // (16384, 8)
    const float* W    = (const float*)d_in[2];   // (128, 64, 64)
    const float* bias = (const float*)d_in[3];   // (8, 8, 64)
    float* out = (float*)d_out;                  // (16384, 8, 64)
    __bf16* wf = (__bf16*)d_ws;                          // 1 MB fragments
    float*  bs = (float*)((char*)d_ws + (1 << 20));      // 64 KB swizzled bias

    wconv_kernel<<<dim3(256), dim3(256), 0, stream>>>(W, wf);
    bconv_kernel<<<dim3(64), dim3(256), 0, stream>>>(bias, bs);
    fused_kernel<<<dim3(1024), dim3(256), 0, stream>>>(x, p, bs, wf, out);
}